// Round 5
// baseline (215.600 us; speedup 1.0000x reference)
//
#include <hip/hip_runtime.h>
#include <hip/hip_bf16.h>

typedef __bf16 bf16x8 __attribute__((ext_vector_type(8)));
typedef float  f32x4  __attribute__((ext_vector_type(4)));
typedef float  f32x16 __attribute__((ext_vector_type(16)));
typedef unsigned int u32;
typedef u32 u32x4 __attribute__((ext_vector_type(4)));

#define MFMA16(a,b,c) __builtin_amdgcn_mfma_f32_16x16x32_bf16(a,b,c,0,0,0)
#define MFMA32(a,b,c) __builtin_amdgcn_mfma_f32_32x32x16_bf16(a,b,c,0,0,0)

constexpr int   Bc = 4, Sc = 2048, Hc = 16, Dc = 64;
constexpr int   HD  = Hc * Dc;        // 1024
constexpr int   SHD = Sc * HD;
constexpr float SCALE = 0.125f;       // 1/sqrt(64)
constexpr float LOG2E = 1.4426950408889634f;
constexpr float QSC   = SCALE * LOG2E;
constexpr float NEG   = -1e30f;
constexpr size_t KV_ELEMS = (size_t)Bc * Hc * Sc * Dc;   // 8388608 per tensor

// ---- prepass: K [b][s][h][d] f32 -> Kb [b][h][s][d] bf16
//               V [b][s][h][d] f32 -> Vt [b][h][d][s] bf16 (transposed)
__global__ __launch_bounds__(256) void prep_kernel(
    const float* __restrict__ K, const float* __restrict__ V,
    __bf16* __restrict__ Kb, __bf16* __restrict__ Vt)
{
    __shared__ __bf16 T[64][72];          // V tile [s_local][d], padded

    const int bid = blockIdx.x;
    const int st  = bid & 31;             // s-tile of 64
    const int h   = (bid >> 5) & 15;
    const int b   = bid >> 9;
    const int tid = threadIdx.x;
    const int sl  = tid >> 2;             // 0..63
    const int d0  = (tid & 3) * 16;
    const int s   = st * 64 + sl;
    const size_t iof  = ((size_t)(b * 2048 + s) * 16 + h) * 64 + d0;
    const size_t hbof = (size_t)(b * 16 + h) * (size_t)(Sc * Dc);

    // K: straight cvt
    {
        const float* src = K + iof;
        __bf16* dst = Kb + hbof + (size_t)s * 64 + d0;
        #pragma unroll
        for (int q = 0; q < 2; ++q) {
            float4 a = *(const float4*)(src + q * 8);
            float4 c = *(const float4*)(src + q * 8 + 4);
            bf16x8 w;
            w[0]=(__bf16)a.x; w[1]=(__bf16)a.y; w[2]=(__bf16)a.z; w[3]=(__bf16)a.w;
            w[4]=(__bf16)c.x; w[5]=(__bf16)c.y; w[6]=(__bf16)c.z; w[7]=(__bf16)c.w;
            *(bf16x8*)(dst + q * 8) = w;
        }
    }
    // V: cvt into LDS tile, then transposed write-out
    {
        const float* src = V + iof;
        #pragma unroll
        for (int q = 0; q < 2; ++q) {
            float4 a = *(const float4*)(src + q * 8);
            float4 c = *(const float4*)(src + q * 8 + 4);
            bf16x8 w;
            w[0]=(__bf16)a.x; w[1]=(__bf16)a.y; w[2]=(__bf16)a.z; w[3]=(__bf16)a.w;
            w[4]=(__bf16)c.x; w[5]=(__bf16)c.y; w[6]=(__bf16)c.z; w[7]=(__bf16)c.w;
            *(bf16x8*)&T[sl][d0 + q * 8] = w;
        }
    }
    __syncthreads();
    {
        const int dl = tid >> 2;          // output row d
        const int s0 = (tid & 3) * 16;
        __bf16* dst = Vt + hbof + (size_t)dl * Sc + st * 64 + s0;
        #pragma unroll
        for (int q = 0; q < 2; ++q) {
            bf16x8 w;
            #pragma unroll
            for (int j = 0; j < 8; ++j) w[j] = T[s0 + q * 8 + j][dl];
            *(bf16x8*)(dst + q * 8) = w;
        }
    }
}

// ---- main: barrier-free, LDS-free streaming flash attention ----
// QK^T: D[row=key][col=q=l31] (A=K-frag, B=Q-frag); 32-key tiles.
// PV  : D[row=d]  [col=q=l31] (A=V^T-frag from global, B=P-frag).
// All softmax state lane-local for q = lane&31.
__global__ __launch_bounds__(256, 3) void fattn3(
    const float* __restrict__ Q, const __bf16* __restrict__ Kb,
    const __bf16* __restrict__ Vt, const int* __restrict__ VL,
    float* __restrict__ O)
{
    const int bid  = blockIdx.x;
    const int l    = (bid & 7) * 128 + (bid >> 3);  // XCD-bijective remap (1024=8*128)
    const int head = l >> 4;                        // 0..63; one head's 16 blocks stay on one XCD
    const int qt4  = l & 15;
    const int b    = head >> 4;
    const int h    = head & 15;
    const int tid  = threadIdx.x;
    const int wid  = tid >> 6;
    const int lane = tid & 63;
    const int l31  = lane & 31;
    const int hi   = lane >> 5;
    const int vl   = VL[b];

    const size_t qbase = (size_t)b * SHD + (size_t)h * Dc;  // f32 [b][s][h][d]
    const __bf16* kb = Kb + (size_t)head * (size_t)(Sc * Dc);
    const __bf16* vt = Vt + (size_t)head * (size_t)(Sc * Dc);

    const int qrow0 = (qt4 * 4 + wid) * 32;

    // Q B-fragments (pre-scaled): lane=col q, k: d = dk*16 + hi*8 + j
    bf16x8 qf[4];
    {
        const float* qp = Q + qbase + (size_t)(qrow0 + l31) * HD + hi * 8;
        #pragma unroll
        for (int dk = 0; dk < 4; ++dk) {
            float4 x0 = *(const float4*)(qp + dk * 16);
            float4 x1 = *(const float4*)(qp + dk * 16 + 4);
            bf16x8 f;
            f[0]=(__bf16)(x0.x*QSC); f[1]=(__bf16)(x0.y*QSC);
            f[2]=(__bf16)(x0.z*QSC); f[3]=(__bf16)(x0.w*QSC);
            f[4]=(__bf16)(x1.x*QSC); f[5]=(__bf16)(x1.y*QSC);
            f[6]=(__bf16)(x1.z*QSC); f[7]=(__bf16)(x1.w*QSC);
            qf[dk] = f;
        }
    }

    f32x16 acc0, acc1;
    #pragma unroll
    for (int i = 0; i < 16; ++i) { acc0[i] = 0.f; acc1[i] = 0.f; }
    float m = NEG, lsum = 0.f;

    const int nt   = (vl + 31) >> 5;
    const int ntm1 = nt - 1;
    const bool hastail = (vl & 31) != 0;

    const __bf16* kRow  = kb + (size_t)l31 * 64 + hi * 8;        // + t*32*64
    const __bf16* vRow0 = vt + (size_t)l31 * Sc + hi * 8;        // d=l31,    + t*32
    const __bf16* vRow1 = vt + (size_t)(32 + l31) * Sc + hi * 8; // d=32+l31, + t*32

    // prologue: loads for t=0
    bf16x8 kf[4], vf00, vf01, vf10, vf11;
    #pragma unroll
    for (int dk = 0; dk < 4; ++dk) kf[dk] = *(const bf16x8*)(kRow + dk * 16);
    vf00 = *(const bf16x8*)(vRow0);      vf01 = *(const bf16x8*)(vRow0 + 16);
    vf10 = *(const bf16x8*)(vRow1);      vf11 = *(const bf16x8*)(vRow1 + 16);

    for (int t = 0; t < nt; ++t) {
        // ---- QK^T (consumes kf(t)) ----
        f32x16 s;
        #pragma unroll
        for (int i = 0; i < 16; ++i) s[i] = 0.f;
        #pragma unroll
        for (int dk = 0; dk < 4; ++dk) s = MFMA32(kf[dk], qf[dk], s);

        // ---- issue K(t+1); hides under softmax+PV ----
        {
            const int off = (((t < ntm1) ? t + 1 : t) << 5) * 64;
            #pragma unroll
            for (int dk = 0; dk < 4; ++dk)
                kf[dk] = *(const bf16x8*)(kRow + off + dk * 16);
        }

        // ---- tail mask: key = 32t + (i&3) + 8*(i>>2) + 4*hi ----
        if (t == ntm1 && hastail) {
            const int kv0 = t * 32;
            #pragma unroll
            for (int i = 0; i < 16; ++i) {
                const int key = kv0 + (i & 3) + 8 * (i >> 2) + 4 * hi;
                if (key >= vl) s[i] = NEG;
            }
        }

        // ---- in-register online softmax (q = l31, lane-local state) ----
        float tm = s[0];
        #pragma unroll
        for (int i = 1; i < 16; ++i) tm = fmaxf(tm, s[i]);
        tm = fmaxf(tm, __shfl_xor(tm, 32));
        if (__any(tm > m)) {              // exact: skipped => fac==1
            const float mn  = fmaxf(m, tm);
            const float fac = __builtin_amdgcn_exp2f(m - mn);
            lsum *= fac;
            #pragma unroll
            for (int i = 0; i < 16; ++i) { acc0[i] *= fac; acc1[i] *= fac; }
            m = mn;
        }
        #pragma unroll
        for (int i = 0; i < 16; ++i) {
            const float p = __builtin_amdgcn_exp2f(s[i] - m);
            s[i] = p; lsum += p;
        }

        // ---- pack P -> bf16, cross-hi redistribute into B-fragments ----
        u32 w[8], sx[8];
        #pragma unroll
        for (int qd = 0; qd < 4; ++qd) {
            asm("v_cvt_pk_bf16_f32 %0, %1, %2" : "=v"(w[2*qd])   : "v"(s[4*qd]),   "v"(s[4*qd+1]));
            asm("v_cvt_pk_bf16_f32 %0, %1, %2" : "=v"(w[2*qd+1]) : "v"(s[4*qd+2]), "v"(s[4*qd+3]));
        }
        #pragma unroll
        for (int j = 0; j < 8; ++j) sx[j] = (u32)__shfl_xor((int)w[j], 32);
        bf16x8 ap[2];
        #pragma unroll
        for (int kt = 0; kt < 2; ++kt) {
            u32x4 fw;
            fw.x = hi ? sx[4*kt+2] : w[4*kt+0];
            fw.y = hi ? sx[4*kt+3] : w[4*kt+1];
            fw.z = hi ? w[4*kt+2] : sx[4*kt+0];
            fw.w = hi ? w[4*kt+3] : sx[4*kt+1];
            ap[kt] = __builtin_bit_cast(bf16x8, fw);
        }

        // ---- PV (consumes vf(t)) ----
        acc0 = MFMA32(vf00, ap[0], acc0);
        acc0 = MFMA32(vf01, ap[1], acc0);
        acc1 = MFMA32(vf10, ap[0], acc1);
        acc1 = MFMA32(vf11, ap[1], acc1);

        // ---- issue V(t+1); hides under next QK^T + softmax ----
        {
            const int off = ((t < ntm1) ? t + 1 : t) << 5;
            vf00 = *(const bf16x8*)(vRow0 + off);
            vf01 = *(const bf16x8*)(vRow0 + off + 16);
            vf10 = *(const bf16x8*)(vRow1 + off);
            vf11 = *(const bf16x8*)(vRow1 + off + 16);
        }
    }

    // ---- epilogue: lane-local normalize, float4 stores ----
    const float lfull = lsum + __shfl_xor(lsum, 32);
    const float linv  = 1.0f / lfull;
    float* op = O + qbase + (size_t)(qrow0 + l31) * HD;
    #pragma unroll
    for (int qd = 0; qd < 4; ++qd) {
        float4 w0, w1;
        w0.x = acc0[4*qd+0]*linv; w0.y = acc0[4*qd+1]*linv;
        w0.z = acc0[4*qd+2]*linv; w0.w = acc0[4*qd+3]*linv;
        w1.x = acc1[4*qd+0]*linv; w1.y = acc1[4*qd+1]*linv;
        w1.z = acc1[4*qd+2]*linv; w1.w = acc1[4*qd+3]*linv;
        *(float4*)(op + qd * 8 + 4 * hi)      = w0;   // d = qd*8+4hi+rr
        *(float4*)(op + 32 + qd * 8 + 4 * hi) = w1;   // d = 32+...
    }
}

// ---------------- fallback (fp32 K/V, no workspace) ------------------------
__global__ __launch_bounds__(256, 2) void fattn_fb(
    const float* __restrict__ Q, const float* __restrict__ K,
    const float* __restrict__ V, const int* __restrict__ VL,
    float* __restrict__ O)
{
    __shared__ __bf16 Vts[64 * 64];
    __shared__ __bf16 Pl[4][32 * 64];
    const int bid = blockIdx.x;
    const int qt = bid & 15, h = (bid >> 4) & 15, b = bid >> 8;
    const int tid = threadIdx.x, wid = tid >> 6, lane = tid & 63;
    const int li = lane & 15, lg = lane >> 4;
    const int vl = VL[b];
    const size_t base = (size_t)b * SHD + (size_t)h * Dc;
    bf16x8 aq[2][2];
    const int qrow0 = qt * 128 + wid * 32;
    #pragma unroll
    for (int m = 0; m < 2; ++m) {
        const float* qp = Q + base + (size_t)(qrow0 + m * 16 + li) * HD + lg * 8;
        #pragma unroll
        for (int ks = 0; ks < 2; ++ks) {
            float4 x0 = *(const float4*)(qp + ks * 32);
            float4 x1 = *(const float4*)(qp + ks * 32 + 4);
            bf16x8 f;
            f[0]=(__bf16)(x0.x*QSC); f[1]=(__bf16)(x0.y*QSC);
            f[2]=(__bf16)(x0.z*QSC); f[3]=(__bf16)(x0.w*QSC);
            f[4]=(__bf16)(x1.x*QSC); f[5]=(__bf16)(x1.y*QSC);
            f[6]=(__bf16)(x1.z*QSC); f[7]=(__bf16)(x1.w*QSC);
            aq[m][ks] = f;
        }
    }
    bf16x8 bones;
    #pragma unroll
    for (int j = 0; j < 8; ++j) bones[j] = (__bf16)1.0f;
    f32x4 acc[2][4]; float mst[2][4], lst[2][4];
    #pragma unroll
    for (int m = 0; m < 2; ++m) {
        #pragma unroll
        for (int r = 0; r < 4; ++r) { mst[m][r] = NEG; lst[m][r] = 0.f; }
        #pragma unroll
        for (int dt = 0; dt < 4; ++dt)
            #pragma unroll
            for (int r = 0; r < 4; ++r) acc[m][dt][r] = 0.f;
    }
    const int ntiles = (vl + 63) >> 6;
    const int sd = tid & 63, skb = (tid >> 6) * 8;
    const float* vpd = V + base + sd;
    for (int t = 0; t < ntiles; ++t) {
        const int kv0 = t * 64;
        __syncthreads();
        #pragma unroll
        for (int rep = 0; rep < 2; ++rep) {
            const int kb2 = skb + rep * 32;
            bf16x8 pk;
            #pragma unroll
            for (int j = 0; j < 8; ++j) pk[j] = (__bf16)vpd[(size_t)(kv0+kb2+j)*HD];
            *(bf16x8*)&Vts[(sd*64+kb2) ^ ((sd&7)<<3)] = pk;
        }
        __syncthreads();
        f32x4 s[2][4];
        #pragma unroll
        for (int m = 0; m < 2; ++m)
            #pragma unroll
            for (int nt = 0; nt < 4; ++nt)
                #pragma unroll
                for (int r = 0; r < 4; ++r) s[m][nt][r] = 0.f;
        #pragma unroll
        for (int nt = 0; nt < 4; ++nt) {
            const float* kp = K + base + (size_t)(kv0+nt*16+li)*HD + lg*8;
            #pragma unroll
            for (int ks = 0; ks < 2; ++ks) {
                float4 x0 = *(const float4*)(kp + ks*32);
                float4 x1 = *(const float4*)(kp + ks*32 + 4);
                bf16x8 f;
                f[0]=(__bf16)x0.x; f[1]=(__bf16)x0.y; f[2]=(__bf16)x0.z; f[3]=(__bf16)x0.w;
                f[4]=(__bf16)x1.x; f[5]=(__bf16)x1.y; f[6]=(__bf16)x1.z; f[7]=(__bf16)x1.w;
                #pragma unroll
                for (int m = 0; m < 2; ++m) s[m][nt] = MFMA16(aq[m][ks], f, s[m][nt]);
            }
        }
        bool kva[4];
        #pragma unroll
        for (int nt = 0; nt < 4; ++nt) kva[nt] = (kv0 + nt*16 + li) < vl;
        #pragma unroll
        for (int m = 0; m < 2; ++m)
            #pragma unroll
            for (int nt = 0; nt < 4; ++nt)
                #pragma unroll
                for (int r = 0; r < 4; ++r)
                    if (!kva[nt]) s[m][nt][r] = NEG;
        #pragma unroll
        for (int m = 0; m < 2; ++m) {
            #pragma unroll
            for (int r = 0; r < 4; ++r) {
                float tm = fmaxf(fmaxf(s[m][0][r], s[m][1][r]),
                                 fmaxf(s[m][2][r], s[m][3][r]));
                tm = fmaxf(tm, __shfl_xor(tm, 1));
                tm = fmaxf(tm, __shfl_xor(tm, 2));
                tm = fmaxf(tm, __shfl_xor(tm, 4));
                tm = fmaxf(tm, __shfl_xor(tm, 8));
                const float mn = fmaxf(mst[m][r], tm);
                const float fac = __builtin_amdgcn_exp2f(mst[m][r] - mn);
                mst[m][r] = mn; lst[m][r] *= fac;
                #pragma unroll
                for (int dt = 0; dt < 4; ++dt) acc[m][dt][r] *= fac;
                const int qr = m*16 + lg*4 + r, swz = (qr & 7) << 3;
                #pragma unroll
                for (int nt = 0; nt < 4; ++nt)
                    Pl[wid][(qr*64 + nt*16 + li) ^ swz] =
                        (__bf16)__builtin_amdgcn_exp2f(s[m][nt][r] - mn);
            }
        }
        bf16x8 ap[2][2];
        #pragma unroll
        for (int m = 0; m < 2; ++m) {
            const int qr = m*16 + li, swz = (qr & 7) << 3;
            #pragma unroll
            for (int ks = 0; ks < 2; ++ks)
                ap[m][ks] = *(bf16x8*)&Pl[wid][(qr*64 + ks*32 + lg*8) ^ swz];
        }
        #pragma unroll
        for (int m = 0; m < 2; ++m) {
            f32x4 rs;
            #pragma unroll
            for (int r = 0; r < 4; ++r) rs[r] = 0.f;
            rs = MFMA16(ap[m][0], bones, rs);
            rs = MFMA16(ap[m][1], bones, rs);
            #pragma unroll
            for (int r = 0; r < 4; ++r) lst[m][r] += rs[r];
        }
        #pragma unroll
        for (int dt = 0; dt < 4; ++dt) {
            const int d = dt*16 + li, swz = (d & 7) << 3;
            #pragma unroll
            for (int ks = 0; ks < 2; ++ks) {
                bf16x8 bv = *(bf16x8*)&Vts[(d*64 + ks*32 + lg*8) ^ swz];
                #pragma unroll
                for (int m = 0; m < 2; ++m)
                    acc[m][dt] = MFMA16(ap[m][ks], bv, acc[m][dt]);
            }
        }
    }
    #pragma unroll
    for (int m = 0; m < 2; ++m) {
        #pragma unroll
        for (int r = 0; r < 4; ++r) {
            const float inv = 1.0f / lst[m][r];
            float* op = O + base + (size_t)(qrow0 + m*16 + lg*4 + r) * HD;
            #pragma unroll
            for (int dt = 0; dt < 4; ++dt) op[dt*16 + li] = acc[m][dt][r] * inv;
        }
    }
}

extern "C" void kernel_launch(void* const* d_in, const int* in_sizes, int n_in,
                              void* d_out, int out_size, void* d_ws, size_t ws_size,
                              hipStream_t stream) {
    (void)in_sizes; (void)n_in; (void)out_size;
    const float* q    = (const float*)d_in[0];
    const float* k    = (const float*)d_in[1];
    const float* v    = (const float*)d_in[2];
    const int*   vlen = (const int*)d_in[3];
    float*       out  = (float*)d_out;
    const size_t need = 2 * KV_ELEMS * sizeof(__bf16);   // 33.5 MB
    if (ws_size >= need) {
        __bf16* kbp = (__bf16*)d_ws;
        __bf16* vtp = kbp + KV_ELEMS;
        prep_kernel<<<dim3(2048), 256, 0, stream>>>(k, v, kbp, vtp);
        fattn3<<<dim3(1024), 256, 0, stream>>>(q, kbp, vtp, vlen, out);
    } else {
        fattn_fb<<<dim3(1024), 256, 0, stream>>>(q, k, v, vlen, out);
    }
}

// Round 7
// 124.910 us; speedup vs baseline: 1.7260x; 1.7260x over previous
//
#include <hip/hip_runtime.h>
#include <hip/hip_bf16.h>

typedef __bf16 bf16x8 __attribute__((ext_vector_type(8)));
typedef float  f32x4  __attribute__((ext_vector_type(4)));
typedef float  f32x16 __attribute__((ext_vector_type(16)));
typedef float  f4     __attribute__((ext_vector_type(4)));   // for nontemporal ops
typedef unsigned int u32;
typedef u32 u32x4 __attribute__((ext_vector_type(4)));

#define MFMA16(a,b,c) __builtin_amdgcn_mfma_f32_16x16x32_bf16(a,b,c,0,0,0)
#define MFMA32(a,b,c) __builtin_amdgcn_mfma_f32_32x32x16_bf16(a,b,c,0,0,0)

constexpr int   Bc = 4, Sc = 2048, Hc = 16, Dc = 64;
constexpr int   HD  = Hc * Dc;        // 1024
constexpr int   SHD = Sc * HD;
constexpr float SCALE = 0.125f;       // 1/sqrt(64)
constexpr float LOG2E = 1.4426950408889634f;
constexpr float QSC   = SCALE * LOG2E;
constexpr float NEG   = -1e30f;
constexpr int   HEAD_ELEMS = Sc * Dc;                    // 131072
constexpr size_t KV_ELEMS  = (size_t)Bc * Hc * HEAD_ELEMS;

// ---- prepass: write K,V as MFMA-fragment-linear bf16 ----------------------
// Kf[head][t][dk][lane][j]       = K[b][t*32 + (lane&31)][h][dk*16 + (lane>>5)*8 + j]
// Vf[head][t][dblk][kt][lane][j] = V[b][t*32 + kt*16 + (lane>>5)*8 + j][h][dblk*32 + (lane&31)]
// (t: 32-key tile; every main-loop load = wave-contiguous 1KB.)
__global__ __launch_bounds__(256) void prep2(
    const float* __restrict__ K, const float* __restrict__ V,
    __bf16* __restrict__ Kf, __bf16* __restrict__ Vf)
{
    __shared__ __align__(16) __bf16 KT[64][80];
    __shared__ __align__(16) __bf16 VT[64][80];

    const int bid = blockIdx.x;
    const int st  = bid & 31;             // s-tile of 64 (= key-tiles 2st, 2st+1)
    const int h   = (bid >> 5) & 15;
    const int b   = bid >> 9;
    const int tid = threadIdx.x;
    const int sl  = tid >> 2;             // 0..63
    const int d0  = (tid & 3) * 16;
    const size_t iof = ((size_t)(b * 2048 + st * 64 + sl) * 16 + h) * 64 + d0;

    #pragma unroll
    for (int q = 0; q < 2; ++q) {
        f4 a = __builtin_nontemporal_load((const f4*)(K + iof + q * 8));
        f4 c = __builtin_nontemporal_load((const f4*)(K + iof + q * 8 + 4));
        bf16x8 w;
        w[0]=(__bf16)a.x; w[1]=(__bf16)a.y; w[2]=(__bf16)a.z; w[3]=(__bf16)a.w;
        w[4]=(__bf16)c.x; w[5]=(__bf16)c.y; w[6]=(__bf16)c.z; w[7]=(__bf16)c.w;
        *(bf16x8*)&KT[sl][d0 + q * 8] = w;
    }
    #pragma unroll
    for (int q = 0; q < 2; ++q) {
        f4 a = __builtin_nontemporal_load((const f4*)(V + iof + q * 8));
        f4 c = __builtin_nontemporal_load((const f4*)(V + iof + q * 8 + 4));
        bf16x8 w;
        w[0]=(__bf16)a.x; w[1]=(__bf16)a.y; w[2]=(__bf16)a.z; w[3]=(__bf16)a.w;
        w[4]=(__bf16)c.x; w[5]=(__bf16)c.y; w[6]=(__bf16)c.z; w[7]=(__bf16)c.w;
        *(bf16x8*)&VT[sl][d0 + q * 8] = w;
    }
    __syncthreads();

    const size_t hbase = (size_t)(b * 16 + h) * HEAD_ELEMS;

    // K fragments: chunk (tl, dk): 64 lanes x 8 elems, coalesced 1KB writes
    #pragma unroll
    for (int it = 0; it < 2; ++it) {
        const int idx = it * 256 + tid;
        const int tl  = idx >> 8;
        const int dk  = (idx >> 6) & 3;
        const int ln  = idx & 63;
        const int l31 = ln & 31, lhi = ln >> 5;
        bf16x8 w = *(const bf16x8*)&KT[tl * 32 + l31][dk * 16 + lhi * 8];
        *(bf16x8*)(Kf + hbase + (size_t)(((st * 2 + tl) * 4 + dk) * 512 + ln * 8)) = w;
    }
    // V fragments (transposed gather from LDS), coalesced 1KB writes
    #pragma unroll
    for (int it = 0; it < 2; ++it) {
        const int idx  = it * 256 + tid;
        const int tl   = idx >> 8;
        const int dblk = (idx >> 7) & 1;
        const int kt2  = (idx >> 6) & 1;
        const int ln   = idx & 63;
        const int l31  = ln & 31, lhi = ln >> 5;
        bf16x8 w;
        #pragma unroll
        for (int j = 0; j < 8; ++j)
            w[j] = VT[tl * 32 + kt2 * 16 + lhi * 8 + j][dblk * 32 + l31];
        *(bf16x8*)(Vf + hbase +
            (size_t)(((((st * 2 + tl) * 2 + dblk) * 2 + kt2)) * 512 + ln * 8)) = w;
    }
}

// ---- main: 1 wave/block, all loads coalesced fragment-linear, no LDS ------
// QK^T: D[row=key][col=q=l31] (A=K-frag, B=Q-frag); PV: D[row=d][col=q=l31]
// (A=V^T-frag, B=P-frag). All softmax state lane-local for q = lane&31.
__global__ __launch_bounds__(64, 4) void fattn4(
    const float* __restrict__ Q, const __bf16* __restrict__ Kf,
    const __bf16* __restrict__ Vf, const int* __restrict__ VL,
    float* __restrict__ O)
{
    const int bid  = blockIdx.x;
    const int l    = (bid & 7) * 512 + (bid >> 3);  // XCD-bijective (4096 = 8*512)
    const int head = l >> 6;                        // 8 heads per XCD chunk
    const int qt   = l & 63;
    const int b    = head >> 4;
    const int h    = head & 15;
    const int lane = threadIdx.x;
    const int l31  = lane & 31;
    const int hi   = lane >> 5;
    const int vl   = VL[b];

    const size_t qbase = (size_t)b * SHD + (size_t)h * Dc;
    const __bf16* kfh = Kf + (size_t)head * HEAD_ELEMS + lane * 8;
    const __bf16* vfh = Vf + (size_t)head * HEAD_ELEMS + lane * 8;
    const int qrow0 = qt * 32;

    // Q B-fragments (pre-scaled), nontemporal: col q = l31, k: d=dk*16+hi*8+j
    bf16x8 qf[4];
    {
        const float* qp = Q + qbase + (size_t)(qrow0 + l31) * HD + hi * 8;
        #pragma unroll
        for (int dk = 0; dk < 4; ++dk) {
            f4 x0 = __builtin_nontemporal_load((const f4*)(qp + dk * 16));
            f4 x1 = __builtin_nontemporal_load((const f4*)(qp + dk * 16 + 4));
            bf16x8 f;
            f[0]=(__bf16)(x0.x*QSC); f[1]=(__bf16)(x0.y*QSC);
            f[2]=(__bf16)(x0.z*QSC); f[3]=(__bf16)(x0.w*QSC);
            f[4]=(__bf16)(x1.x*QSC); f[5]=(__bf16)(x1.y*QSC);
            f[6]=(__bf16)(x1.z*QSC); f[7]=(__bf16)(x1.w*QSC);
            qf[dk] = f;
        }
    }

    f32x16 acc0, acc1;
    #pragma unroll
    for (int i = 0; i < 16; ++i) { acc0[i] = 0.f; acc1[i] = 0.f; }
    float m = NEG, lsum = 0.f;

    const int nt   = (vl + 31) >> 5;
    const int ntm1 = nt - 1;
    const bool hastail = (vl & 31) != 0;

    bf16x8 kf[4], vf[4];
    #pragma unroll
    for (int dk = 0; dk < 4; ++dk) kf[dk] = *(const bf16x8*)(kfh + dk * 512);
    #pragma unroll
    for (int i = 0; i < 4; ++i)   vf[i]  = *(const bf16x8*)(vfh + i * 512);

    for (int t = 0; t < nt; ++t) {
        // ---- QK^T (consumes kf(t)) ----
        f32x16 s;
        #pragma unroll
        for (int i = 0; i < 16; ++i) s[i] = 0.f;
        #pragma unroll
        for (int dk = 0; dk < 4; ++dk) s = MFMA32(kf[dk], qf[dk], s);

        // ---- issue K(t+1): coalesced 1KB loads, hide under softmax+PV ----
        {
            const size_t off = (size_t)((t < ntm1) ? t + 1 : t) * 2048;
            #pragma unroll
            for (int dk = 0; dk < 4; ++dk)
                kf[dk] = *(const bf16x8*)(kfh + off + dk * 512);
        }

        // ---- tail mask: key = 32t + (i&3) + 8*(i>>2) + 4*hi ----
        if (t == ntm1 && hastail) {
            const int kv0 = t * 32;
            #pragma unroll
            for (int i = 0; i < 16; ++i) {
                const int key = kv0 + (i & 3) + 8 * (i >> 2) + 4 * hi;
                if (key >= vl) s[i] = NEG;
            }
        }

        // ---- tree max ----
        float a0 = fmaxf(s[0], s[1]),  a1 = fmaxf(s[2], s[3]);
        float a2 = fmaxf(s[4], s[5]),  a3 = fmaxf(s[6], s[7]);
        float a4 = fmaxf(s[8], s[9]),  a5 = fmaxf(s[10], s[11]);
        float a6 = fmaxf(s[12], s[13]), a7 = fmaxf(s[14], s[15]);
        float b0 = fmaxf(a0, a1), b1 = fmaxf(a2, a3);
        float b2 = fmaxf(a4, a5), b3 = fmaxf(a6, a7);
        float tm = fmaxf(fmaxf(b0, b1), fmaxf(b2, b3));
        tm = fmaxf(tm, __shfl_xor(tm, 32));

        // ---- defer-max: rescale only if max grew by > 8 (log2 domain) ----
        if (__any(tm > m + 8.0f)) {
            const float mn  = fmaxf(m, tm);
            const float fac = __builtin_amdgcn_exp2f(m - mn);
            lsum *= fac;
            #pragma unroll
            for (int i = 0; i < 16; ++i) { acc0[i] *= fac; acc1[i] *= fac; }
            m = mn;
        }
        #pragma unroll
        for (int i = 0; i < 16; ++i)
            s[i] = __builtin_amdgcn_exp2f(s[i] - m);
        // tree sum -> one dependent add into lsum
        {
            float t0 = (s[0]+s[1]) + (s[2]+s[3]);
            float t1 = (s[4]+s[5]) + (s[6]+s[7]);
            float t2 = (s[8]+s[9]) + (s[10]+s[11]);
            float t3 = (s[12]+s[13]) + (s[14]+s[15]);
            lsum += (t0 + t1) + (t2 + t3);
        }

        // ---- pack P -> bf16, cross-hi redistribute into B-fragments ----
        bf16x8 ap[2];
        #pragma unroll
        for (int kt = 0; kt < 2; ++kt) {
            u32 w0, w1, w2, w3;
            asm("v_cvt_pk_bf16_f32 %0, %1, %2" : "=v"(w0) : "v"(s[8*kt+0]), "v"(s[8*kt+1]));
            asm("v_cvt_pk_bf16_f32 %0, %1, %2" : "=v"(w1) : "v"(s[8*kt+2]), "v"(s[8*kt+3]));
            asm("v_cvt_pk_bf16_f32 %0, %1, %2" : "=v"(w2) : "v"(s[8*kt+4]), "v"(s[8*kt+5]));
            asm("v_cvt_pk_bf16_f32 %0, %1, %2" : "=v"(w3) : "v"(s[8*kt+6]), "v"(s[8*kt+7]));
            const u32 sx0 = (u32)__shfl_xor((int)w0, 32);
            const u32 sx1 = (u32)__shfl_xor((int)w1, 32);
            const u32 sx2 = (u32)__shfl_xor((int)w2, 32);
            const u32 sx3 = (u32)__shfl_xor((int)w3, 32);
            u32x4 fw;
            fw.x = hi ? sx2 : w0;
            fw.y = hi ? sx3 : w1;
            fw.z = hi ? w2 : sx0;
            fw.w = hi ? w3 : sx1;
            ap[kt] = __builtin_bit_cast(bf16x8, fw);
        }

        // ---- PV (consumes vf(t)) ----
        acc0 = MFMA32(vf[0], ap[0], acc0);
        acc0 = MFMA32(vf[1], ap[1], acc0);
        acc1 = MFMA32(vf[2], ap[0], acc1);
        acc1 = MFMA32(vf[3], ap[1], acc1);

        // ---- issue V(t+1): coalesced 1KB loads ----
        {
            const size_t off = (size_t)((t < ntm1) ? t + 1 : t) * 2048;
            #pragma unroll
            for (int i = 0; i < 4; ++i)
                vf[i] = *(const bf16x8*)(vfh + off + i * 512);
        }
    }

    // ---- epilogue: lane-local normalize, nontemporal f4 stores ----
    const float lfull = lsum + __shfl_xor(lsum, 32);
    const float linv  = 1.0f / lfull;
    float* op = O + qbase + (size_t)(qrow0 + l31) * HD;
    #pragma unroll
    for (int qd = 0; qd < 4; ++qd) {
        f4 w0, w1;
        w0.x = acc0[4*qd+0]*linv; w0.y = acc0[4*qd+1]*linv;
        w0.z = acc0[4*qd+2]*linv; w0.w = acc0[4*qd+3]*linv;
        w1.x = acc1[4*qd+0]*linv; w1.y = acc1[4*qd+1]*linv;
        w1.z = acc1[4*qd+2]*linv; w1.w = acc1[4*qd+3]*linv;
        __builtin_nontemporal_store(w0, (f4*)(op + qd * 8 + 4 * hi));
        __builtin_nontemporal_store(w1, (f4*)(op + 32 + qd * 8 + 4 * hi));
    }
}

// ---------------- fallback (fp32 K/V, no workspace) ------------------------
__global__ __launch_bounds__(256, 2) void fattn_fb(
    const float* __restrict__ Q, const float* __restrict__ K,
    const float* __restrict__ V, const int* __restrict__ VL,
    float* __restrict__ O)
{
    __shared__ __bf16 Vts[64 * 64];
    __shared__ __bf16 Pl[4][32 * 64];
    const int bid = blockIdx.x;
    const int qt = bid & 15, h = (bid >> 4) & 15, b = bid >> 8;
    const int tid = threadIdx.x, wid = tid >> 6, lane = tid & 63;
    const int li = lane & 15, lg = lane >> 4;
    const int vl = VL[b];
    const size_t base = (size_t)b * SHD + (size_t)h * Dc;
    bf16x8 aq[2][2];
    const int qrow0 = qt * 128 + wid * 32;
    #pragma unroll
    for (int m = 0; m < 2; ++m) {
        const float* qp = Q + base + (size_t)(qrow0 + m * 16 + li) * HD + lg * 8;
        #pragma unroll
        for (int ks = 0; ks < 2; ++ks) {
            float4 x0 = *(const float4*)(qp + ks * 32);
            float4 x1 = *(const float4*)(qp + ks * 32 + 4);
            bf16x8 f;
            f[0]=(__bf16)(x0.x*QSC); f[1]=(__bf16)(x0.y*QSC);
            f[2]=(__bf16)(x0.z*QSC); f[3]=(__bf16)(x0.w*QSC);
            f[4]=(__bf16)(x1.x*QSC); f[5]=(__bf16)(x1.y*QSC);
            f[6]=(__bf16)(x1.z*QSC); f[7]=(__bf16)(x1.w*QSC);
            aq[m][ks] = f;
        }
    }
    bf16x8 bones;
    #pragma unroll
    for (int j = 0; j < 8; ++j) bones[j] = (__bf16)1.0f;
    f32x4 acc[2][4]; float mst[2][4], lst[2][4];
    #pragma unroll
    for (int m = 0; m < 2; ++m) {
        #pragma unroll
        for (int r = 0; r < 4; ++r) { mst[m][r] = NEG; lst[m][r] = 0.f; }
        #pragma unroll
        for (int dt = 0; dt < 4; ++dt)
            #pragma unroll
            for (int r = 0; r < 4; ++r) acc[m][dt][r] = 0.f;
    }
    const int ntiles = (vl + 63) >> 6;
    const int sd = tid & 63, skb = (tid >> 6) * 8;
    const float* vpd = V + base + sd;
    for (int t = 0; t < ntiles; ++t) {
        const int kv0 = t * 64;
        __syncthreads();
        #pragma unroll
        for (int rep = 0; rep < 2; ++rep) {
            const int kb2 = skb + rep * 32;
            bf16x8 pk;
            #pragma unroll
            for (int j = 0; j < 8; ++j) pk[j] = (__bf16)vpd[(size_t)(kv0+kb2+j)*HD];
            *(bf16x8*)&Vts[(sd*64+kb2) ^ ((sd&7)<<3)] = pk;
        }
        __syncthreads();
        f32x4 s[2][4];
        #pragma unroll
        for (int m = 0; m < 2; ++m)
            #pragma unroll
            for (int nt2 = 0; nt2 < 4; ++nt2)
                #pragma unroll
                for (int r = 0; r < 4; ++r) s[m][nt2][r] = 0.f;
        #pragma unroll
        for (int nt2 = 0; nt2 < 4; ++nt2) {
            const float* kp = K + base + (size_t)(kv0+nt2*16+li)*HD + lg*8;
            #pragma unroll
            for (int ks = 0; ks < 2; ++ks) {
                float4 x0 = *(const float4*)(kp + ks*32);
                float4 x1 = *(const float4*)(kp + ks*32 + 4);
                bf16x8 f;
                f[0]=(__bf16)x0.x; f[1]=(__bf16)x0.y; f[2]=(__bf16)x0.z; f[3]=(__bf16)x0.w;
                f[4]=(__bf16)x1.x; f[5]=(__bf16)x1.y; f[6]=(__bf16)x1.z; f[7]=(__bf16)x1.w;
                #pragma unroll
                for (int m = 0; m < 2; ++m) s[m][nt2] = MFMA16(aq[m][ks], f, s[m][nt2]);
            }
        }
        bool kva[4];
        #pragma unroll
        for (int nt2 = 0; nt2 < 4; ++nt2) kva[nt2] = (kv0 + nt2*16 + li) < vl;
        #pragma unroll
        for (int m = 0; m < 2; ++m)
            #pragma unroll
            for (int nt2 = 0; nt2 < 4; ++nt2)
                #pragma unroll
                for (int r = 0; r < 4; ++r)
                    if (!kva[nt2]) s[m][nt2][r] = NEG;
        #pragma unroll
        for (int m = 0; m < 2; ++m) {
            #pragma unroll
            for (int r = 0; r < 4; ++r) {
                float tmx = fmaxf(fmaxf(s[m][0][r], s[m][1][r]),
                                  fmaxf(s[m][2][r], s[m][3][r]));
                tmx = fmaxf(tmx, __shfl_xor(tmx, 1));
                tmx = fmaxf(tmx, __shfl_xor(tmx, 2));
                tmx = fmaxf(tmx, __shfl_xor(tmx, 4));
                tmx = fmaxf(tmx, __shfl_xor(tmx, 8));
                const float mn = fmaxf(mst[m][r], tmx);
                const float fac = __builtin_amdgcn_exp2f(mst[m][r] - mn);
                mst[m][r] = mn; lst[m][r] *= fac;
                #pragma unroll
                for (int dt = 0; dt < 4; ++dt) acc[m][dt][r] *= fac;
                const int qr = m*16 + lg*4 + r, swz = (qr & 7) << 3;
                #pragma unroll
                for (int nt2 = 0; nt2 < 4; ++nt2)
                    Pl[wid][(qr*64 + nt2*16 + li) ^ swz] =
                        (__bf16)__builtin_amdgcn_exp2f(s[m][nt2][r] - mn);
            }
        }
        bf16x8 ap[2][2];
        #pragma unroll
        for (int m = 0; m < 2; ++m) {
            const int qr = m*16 + li, swz = (qr & 7) << 3;
            #pragma unroll
            for (int ks = 0; ks < 2; ++ks)
                ap[m][ks] = *(bf16x8*)&Pl[wid][(qr*64 + ks*32 + lg*8) ^ swz];
        }
        #pragma unroll
        for (int m = 0; m < 2; ++m) {
            f32x4 rs;
            #pragma unroll
            for (int r = 0; r < 4; ++r) rs[r] = 0.f;
            rs = MFMA16(ap[m][0], bones, rs);
            rs = MFMA16(ap[m][1], bones, rs);
            #pragma unroll
            for (int r = 0; r < 4; ++r) lst[m][r] += rs[r];
        }
        #pragma unroll
        for (int dt = 0; dt < 4; ++dt) {
            const int d = dt*16 + li, swz = (d & 7) << 3;
            #pragma unroll
            for (int ks = 0; ks < 2; ++ks) {
                bf16x8 bv = *(bf16x8*)&Vts[(d*64 + ks*32 + lg*8) ^ swz];
                #pragma unroll
                for (int m = 0; m < 2; ++m)
                    acc[m][dt] = MFMA16(ap[m][ks], bv, acc[m][dt]);
            }
        }
    }
    #pragma unroll
    for (int m = 0; m < 2; ++m) {
        #pragma unroll
        for (int r = 0; r < 4; ++r) {
            const float inv = 1.0f / lst[m][r];
            float* op = O + base + (size_t)(qrow0 + m*16 + lg*4 + r) * HD;
            #pragma unroll
            for (int dt = 0; dt < 4; ++dt) op[dt*16 + li] = acc[m][dt][r] * inv;
        }
    }
}

extern "C" void kernel_launch(void* const* d_in, const int* in_sizes, int n_in,
                              void* d_out, int out_size, void* d_ws, size_t ws_size,
                              hipStream_t stream) {
    (void)in_sizes; (void)n_in; (void)out_size;
    const float* q    = (const float*)d_in[0];
    const float* k    = (const float*)d_in[1];
    const float* v    = (const float*)d_in[2];
    const int*   vlen = (const int*)d_in[3];
    float*       out  = (float*)d_out;
    const size_t need = 2 * KV_ELEMS * sizeof(__bf16);   // 33.5 MB
    if (ws_size >= need) {
        __bf16* kfp = (__bf16*)d_ws;
        __bf16* vfp = kfp + KV_ELEMS;
        prep2<<<dim3(2048), 256, 0, stream>>>(k, v, kfp, vfp);
        fattn4<<<dim3(4096), 64, 0, stream>>>(q, kfp, vfp, vlen, out);
    } else {
        fattn_fb<<<dim3(1024), 256, 0, stream>>>(q, k, v, vlen, out);
    }
}

// Round 8
// 117.605 us; speedup vs baseline: 1.8333x; 1.0621x over previous
//
#include <hip/hip_runtime.h>
#include <hip/hip_bf16.h>

typedef __bf16 bf16x8 __attribute__((ext_vector_type(8)));
typedef float  f32x4  __attribute__((ext_vector_type(4)));
typedef float  f32x16 __attribute__((ext_vector_type(16)));
typedef float  f4     __attribute__((ext_vector_type(4)));   // for nontemporal ops
typedef unsigned int u32;
typedef u32 u32x4 __attribute__((ext_vector_type(4)));

#define MFMA16(a,b,c) __builtin_amdgcn_mfma_f32_16x16x32_bf16(a,b,c,0,0,0)
#define MFMA32(a,b,c) __builtin_amdgcn_mfma_f32_32x32x16_bf16(a,b,c,0,0,0)

constexpr int   Bc = 4, Sc = 2048, Hc = 16, Dc = 64;
constexpr int   HD  = Hc * Dc;        // 1024
constexpr int   SHD = Sc * HD;
constexpr float SCALE = 0.125f;       // 1/sqrt(64)
constexpr float LOG2E = 1.4426950408889634f;
constexpr float QSC   = SCALE * LOG2E;
constexpr float NEG   = -1e30f;
constexpr int   HEAD_ELEMS = Sc * Dc;                    // 131072
constexpr size_t KV_ELEMS  = (size_t)Bc * Hc * HEAD_ELEMS;

// ---- prepass: write K,V as MFMA-fragment-linear bf16 ----------------------
// Kf[head][t][dk][lane][j]       = K[b][t*32 + (lane&31)][h][dk*16 + (lane>>5)*8 + j]
// Vf[head][t][dblk][kt][lane][j] = V[b][t*32 + kt*16 + (lane>>5)*8 + j][h][dblk*32 + (lane&31)]
// (t: 32-key tile; every main-loop load = wave-contiguous 1KB.)
__global__ __launch_bounds__(256) void prep2(
    const float* __restrict__ K, const float* __restrict__ V,
    __bf16* __restrict__ Kf, __bf16* __restrict__ Vf)
{
    __shared__ __align__(16) __bf16 KT[64][80];
    __shared__ __align__(16) __bf16 VT[64][80];

    const int bid = blockIdx.x;
    const int st  = bid & 31;             // s-tile of 64 (= key-tiles 2st, 2st+1)
    const int h   = (bid >> 5) & 15;
    const int b   = bid >> 9;
    const int tid = threadIdx.x;
    const int sl  = tid >> 2;             // 0..63
    const int d0  = (tid & 3) * 16;
    const size_t iof = ((size_t)(b * 2048 + st * 64 + sl) * 16 + h) * 64 + d0;

    #pragma unroll
    for (int q = 0; q < 2; ++q) {
        f4 a = __builtin_nontemporal_load((const f4*)(K + iof + q * 8));
        f4 c = __builtin_nontemporal_load((const f4*)(K + iof + q * 8 + 4));
        bf16x8 w;
        w[0]=(__bf16)a.x; w[1]=(__bf16)a.y; w[2]=(__bf16)a.z; w[3]=(__bf16)a.w;
        w[4]=(__bf16)c.x; w[5]=(__bf16)c.y; w[6]=(__bf16)c.z; w[7]=(__bf16)c.w;
        *(bf16x8*)&KT[sl][d0 + q * 8] = w;
    }
    #pragma unroll
    for (int q = 0; q < 2; ++q) {
        f4 a = __builtin_nontemporal_load((const f4*)(V + iof + q * 8));
        f4 c = __builtin_nontemporal_load((const f4*)(V + iof + q * 8 + 4));
        bf16x8 w;
        w[0]=(__bf16)a.x; w[1]=(__bf16)a.y; w[2]=(__bf16)a.z; w[3]=(__bf16)a.w;
        w[4]=(__bf16)c.x; w[5]=(__bf16)c.y; w[6]=(__bf16)c.z; w[7]=(__bf16)c.w;
        *(bf16x8*)&VT[sl][d0 + q * 8] = w;
    }
    __syncthreads();

    const size_t hbase = (size_t)(b * 16 + h) * HEAD_ELEMS;

    // K fragments: chunk (tl, dk): 64 lanes x 8 elems, coalesced 1KB writes
    #pragma unroll
    for (int it = 0; it < 2; ++it) {
        const int idx = it * 256 + tid;
        const int tl  = idx >> 8;
        const int dk  = (idx >> 6) & 3;
        const int ln  = idx & 63;
        const int l31 = ln & 31, lhi = ln >> 5;
        bf16x8 w = *(const bf16x8*)&KT[tl * 32 + l31][dk * 16 + lhi * 8];
        *(bf16x8*)(Kf + hbase + (size_t)(((st * 2 + tl) * 4 + dk) * 512 + ln * 8)) = w;
    }
    // V fragments (transposed gather from LDS), coalesced 1KB writes
    #pragma unroll
    for (int it = 0; it < 2; ++it) {
        const int idx  = it * 256 + tid;
        const int tl   = idx >> 8;
        const int dblk = (idx >> 7) & 1;
        const int kt2  = (idx >> 6) & 1;
        const int ln   = idx & 63;
        const int l31  = ln & 31, lhi = ln >> 5;
        bf16x8 w;
        #pragma unroll
        for (int j = 0; j < 8; ++j)
            w[j] = VT[tl * 32 + kt2 * 16 + lhi * 8 + j][dblk * 32 + l31];
        *(bf16x8*)(Vf + hbase +
            (size_t)(((((st * 2 + tl) * 2 + dblk) * 2 + kt2)) * 512 + ln * 8)) = w;
    }
}

// ---- main: 1 wave/block, all loads coalesced fragment-linear, no LDS ------
// QK^T: D[row=key][col=q=l31] (A=K-frag, B=Q-frag); PV: D[row=d][col=q=l31]
// (A=V^T-frag, B=P-frag). All softmax state lane-local for q = lane&31.
// b-balanced XCD map: head = xcd + (idx&7)*8 -> each XCD gets 2 heads of
// every batch (equal work mix) while a head's 64 q-blocks stay on one XCD.
__global__ __launch_bounds__(64, 4) void fattn4(
    const float* __restrict__ Q, const __bf16* __restrict__ Kf,
    const __bf16* __restrict__ Vf, const int* __restrict__ VL,
    float* __restrict__ O)
{
    const int bid  = blockIdx.x;
    const int xcd  = bid & 7;
    const int idx  = bid >> 3;
    const int head = xcd + (idx & 7) * 8;   // head mod 8 == xcd
    const int qt   = idx >> 3;              // 0..63
    const int b    = head >> 4;
    const int h    = head & 15;
    const int lane = threadIdx.x;
    const int l31  = lane & 31;
    const int hi   = lane >> 5;
    const int vl   = VL[b];

    const size_t qbase = (size_t)b * SHD + (size_t)h * Dc;
    const __bf16* kfh = Kf + (size_t)head * HEAD_ELEMS + lane * 8;
    const __bf16* vfh = Vf + (size_t)head * HEAD_ELEMS + lane * 8;
    const int qrow0 = qt * 32;

    // Q B-fragments (pre-scaled), nontemporal: col q = l31, k: d=dk*16+hi*8+j
    bf16x8 qf[4];
    {
        const float* qp = Q + qbase + (size_t)(qrow0 + l31) * HD + hi * 8;
        #pragma unroll
        for (int dk = 0; dk < 4; ++dk) {
            f4 x0 = __builtin_nontemporal_load((const f4*)(qp + dk * 16));
            f4 x1 = __builtin_nontemporal_load((const f4*)(qp + dk * 16 + 4));
            bf16x8 f;
            f[0]=(__bf16)(x0.x*QSC); f[1]=(__bf16)(x0.y*QSC);
            f[2]=(__bf16)(x0.z*QSC); f[3]=(__bf16)(x0.w*QSC);
            f[4]=(__bf16)(x1.x*QSC); f[5]=(__bf16)(x1.y*QSC);
            f[6]=(__bf16)(x1.z*QSC); f[7]=(__bf16)(x1.w*QSC);
            qf[dk] = f;
        }
    }

    f32x16 acc0, acc1;
    #pragma unroll
    for (int i = 0; i < 16; ++i) { acc0[i] = 0.f; acc1[i] = 0.f; }
    float m = NEG, lsum = 0.f;

    const int nt   = (vl + 31) >> 5;
    const int ntm1 = nt - 1;
    const bool hastail = (vl & 31) != 0;

    bf16x8 kf[4], vf[4];
    #pragma unroll
    for (int dk = 0; dk < 4; ++dk) kf[dk] = *(const bf16x8*)(kfh + dk * 512);
    #pragma unroll
    for (int i = 0; i < 4; ++i)   vf[i]  = *(const bf16x8*)(vfh + i * 512);

    for (int t = 0; t < nt; ++t) {
        // ---- QK^T (consumes kf(t)) ----
        f32x16 s;
        #pragma unroll
        for (int i = 0; i < 16; ++i) s[i] = 0.f;
        #pragma unroll
        for (int dk = 0; dk < 4; ++dk) s = MFMA32(kf[dk], qf[dk], s);

        // ---- issue K(t+1): coalesced 1KB loads, hide under softmax+PV ----
        {
            const size_t off = (size_t)((t < ntm1) ? t + 1 : t) * 2048;
            #pragma unroll
            for (int dk = 0; dk < 4; ++dk)
                kf[dk] = *(const bf16x8*)(kfh + off + dk * 512);
        }

        // ---- tail mask: key = 32t + (i&3) + 8*(i>>2) + 4*hi ----
        if (t == ntm1 && hastail) {
            const int kv0 = t * 32;
            #pragma unroll
            for (int i = 0; i < 16; ++i) {
                const int key = kv0 + (i & 3) + 8 * (i >> 2) + 4 * hi;
                if (key >= vl) s[i] = NEG;
            }
        }

        // ---- max tree (max3-fusable groupings) ----
        float c0 = fmaxf(fmaxf(s[0],  s[1]),  s[2]);
        float c1 = fmaxf(fmaxf(s[3],  s[4]),  s[5]);
        float c2 = fmaxf(fmaxf(s[6],  s[7]),  s[8]);
        float c3 = fmaxf(fmaxf(s[9],  s[10]), s[11]);
        float c4 = fmaxf(fmaxf(s[12], s[13]), s[14]);
        float c5 = fmaxf(fmaxf(c0, c1), s[15]);
        float c6 = fmaxf(fmaxf(c2, c3), c4);
        float tm = fmaxf(c5, c6);
        tm = fmaxf(tm, __shfl_xor(tm, 32));

        // ---- defer-max: rescale only if max grew by > 8 (log2 domain) ----
        if (__any(tm > m + 8.0f)) {
            const float mn  = fmaxf(m, tm);
            const float fac = __builtin_amdgcn_exp2f(m - mn);
            lsum *= fac;
            #pragma unroll
            for (int i = 0; i < 16; ++i) { acc0[i] *= fac; acc1[i] *= fac; }
            m = mn;
        }
        #pragma unroll
        for (int i = 0; i < 16; ++i)
            s[i] = __builtin_amdgcn_exp2f(s[i] - m);
        // tree sum -> one dependent add into lsum
        {
            float t0 = (s[0]+s[1]) + (s[2]+s[3]);
            float t1 = (s[4]+s[5]) + (s[6]+s[7]);
            float t2 = (s[8]+s[9]) + (s[10]+s[11]);
            float t3 = (s[12]+s[13]) + (s[14]+s[15]);
            lsum += (t0 + t1) + (t2 + t3);
        }

        // ---- pack P -> bf16; cross-half redistribute via permlane32_swap --
        // swap(a,b): a.hi32lanes <-> b.lo32lanes  =>
        //   a' = {a(own) lo-lanes | b(from lane-32) hi-lanes} = fw.x
        //   b' = {a(from lane+32) lo-lanes | b(own) hi-lanes} = fw.z
        bf16x8 ap[2];
        #pragma unroll
        for (int kt = 0; kt < 2; ++kt) {
            u32 w0, w1, w2, w3;
            asm("v_cvt_pk_bf16_f32 %0, %1, %2" : "=v"(w0) : "v"(s[8*kt+0]), "v"(s[8*kt+1]));
            asm("v_cvt_pk_bf16_f32 %0, %1, %2" : "=v"(w1) : "v"(s[8*kt+2]), "v"(s[8*kt+3]));
            asm("v_cvt_pk_bf16_f32 %0, %1, %2" : "=v"(w2) : "v"(s[8*kt+4]), "v"(s[8*kt+5]));
            asm("v_cvt_pk_bf16_f32 %0, %1, %2" : "=v"(w3) : "v"(s[8*kt+6]), "v"(s[8*kt+7]));
            asm("v_permlane32_swap_b32 %0, %1" : "+v"(w0), "+v"(w2));
            asm("v_permlane32_swap_b32 %0, %1" : "+v"(w1), "+v"(w3));
            u32x4 fw;
            fw.x = w0;   // hi ? sx2 : w0
            fw.y = w1;   // hi ? sx3 : w1
            fw.z = w2;   // hi ? w2  : sx0
            fw.w = w3;   // hi ? w3  : sx1
            ap[kt] = __builtin_bit_cast(bf16x8, fw);
        }

        // ---- PV (consumes vf(t)) ----
        acc0 = MFMA32(vf[0], ap[0], acc0);
        acc0 = MFMA32(vf[1], ap[1], acc0);
        acc1 = MFMA32(vf[2], ap[0], acc1);
        acc1 = MFMA32(vf[3], ap[1], acc1);

        // ---- issue V(t+1): coalesced 1KB loads ----
        {
            const size_t off = (size_t)((t < ntm1) ? t + 1 : t) * 2048;
            #pragma unroll
            for (int i = 0; i < 4; ++i)
                vf[i] = *(const bf16x8*)(vfh + off + i * 512);
        }
    }

    // ---- epilogue: lane-local normalize, regular f4 stores (L2 combines) --
    const float lfull = lsum + __shfl_xor(lsum, 32);
    const float linv  = 1.0f / lfull;
    float* op = O + qbase + (size_t)(qrow0 + l31) * HD;
    #pragma unroll
    for (int qd = 0; qd < 4; ++qd) {
        f4 w0, w1;
        w0.x = acc0[4*qd+0]*linv; w0.y = acc0[4*qd+1]*linv;
        w0.z = acc0[4*qd+2]*linv; w0.w = acc0[4*qd+3]*linv;
        w1.x = acc1[4*qd+0]*linv; w1.y = acc1[4*qd+1]*linv;
        w1.z = acc1[4*qd+2]*linv; w1.w = acc1[4*qd+3]*linv;
        *(f4*)(op + qd * 8 + 4 * hi)      = w0;
        *(f4*)(op + 32 + qd * 8 + 4 * hi) = w1;
    }
}

// ---------------- fallback (fp32 K/V, no workspace) ------------------------
__global__ __launch_bounds__(256, 2) void fattn_fb(
    const float* __restrict__ Q, const float* __restrict__ K,
    const float* __restrict__ V, const int* __restrict__ VL,
    float* __restrict__ O)
{
    __shared__ __bf16 Vts[64 * 64];
    __shared__ __bf16 Pl[4][32 * 64];
    const int bid = blockIdx.x;
    const int qt = bid & 15, h = (bid >> 4) & 15, b = bid >> 8;
    const int tid = threadIdx.x, wid = tid >> 6, lane = tid & 63;
    const int li = lane & 15, lg = lane >> 4;
    const int vl = VL[b];
    const size_t base = (size_t)b * SHD + (size_t)h * Dc;
    bf16x8 aq[2][2];
    const int qrow0 = qt * 128 + wid * 32;
    #pragma unroll
    for (int m = 0; m < 2; ++m) {
        const float* qp = Q + base + (size_t)(qrow0 + m * 16 + li) * HD + lg * 8;
        #pragma unroll
        for (int ks = 0; ks < 2; ++ks) {
            float4 x0 = *(const float4*)(qp + ks * 32);
            float4 x1 = *(const float4*)(qp + ks * 32 + 4);
            bf16x8 f;
            f[0]=(__bf16)(x0.x*QSC); f[1]=(__bf16)(x0.y*QSC);
            f[2]=(__bf16)(x0.z*QSC); f[3]=(__bf16)(x0.w*QSC);
            f[4]=(__bf16)(x1.x*QSC); f[5]=(__bf16)(x1.y*QSC);
            f[6]=(__bf16)(x1.z*QSC); f[7]=(__bf16)(x1.w*QSC);
            aq[m][ks] = f;
        }
    }
    bf16x8 bones;
    #pragma unroll
    for (int j = 0; j < 8; ++j) bones[j] = (__bf16)1.0f;
    f32x4 acc[2][4]; float mst[2][4], lst[2][4];
    #pragma unroll
    for (int m = 0; m < 2; ++m) {
        #pragma unroll
        for (int r = 0; r < 4; ++r) { mst[m][r] = NEG; lst[m][r] = 0.f; }
        #pragma unroll
        for (int dt = 0; dt < 4; ++dt)
            #pragma unroll
            for (int r = 0; r < 4; ++r) acc[m][dt][r] = 0.f;
    }
    const int ntiles = (vl + 63) >> 6;
    const int sd = tid & 63, skb = (tid >> 6) * 8;
    const float* vpd = V + base + sd;
    for (int t = 0; t < ntiles; ++t) {
        const int kv0 = t * 64;
        __syncthreads();
        #pragma unroll
        for (int rep = 0; rep < 2; ++rep) {
            const int kb2 = skb + rep * 32;
            bf16x8 pk;
            #pragma unroll
            for (int j = 0; j < 8; ++j) pk[j] = (__bf16)vpd[(size_t)(kv0+kb2+j)*HD];
            *(bf16x8*)&Vts[(sd*64+kb2) ^ ((sd&7)<<3)] = pk;
        }
        __syncthreads();
        f32x4 s[2][4];
        #pragma unroll
        for (int m = 0; m < 2; ++m)
            #pragma unroll
            for (int nt2 = 0; nt2 < 4; ++nt2)
                #pragma unroll
                for (int r = 0; r < 4; ++r) s[m][nt2][r] = 0.f;
        #pragma unroll
        for (int nt2 = 0; nt2 < 4; ++nt2) {
            const float* kp = K + base + (size_t)(kv0+nt2*16+li)*HD + lg*8;
            #pragma unroll
            for (int ks = 0; ks < 2; ++ks) {
                float4 x0 = *(const float4*)(kp + ks*32);
                float4 x1 = *(const float4*)(kp + ks*32 + 4);
                bf16x8 f;
                f[0]=(__bf16)x0.x; f[1]=(__bf16)x0.y; f[2]=(__bf16)x0.z; f[3]=(__bf16)x0.w;
                f[4]=(__bf16)x1.x; f[5]=(__bf16)x1.y; f[6]=(__bf16)x1.z; f[7]=(__bf16)x1.w;
                #pragma unroll
                for (int m = 0; m < 2; ++m) s[m][nt2] = MFMA16(aq[m][ks], f, s[m][nt2]);
            }
        }
        bool kva[4];
        #pragma unroll
        for (int nt2 = 0; nt2 < 4; ++nt2) kva[nt2] = (kv0 + nt2*16 + li) < vl;
        #pragma unroll
        for (int m = 0; m < 2; ++m)
            #pragma unroll
            for (int nt2 = 0; nt2 < 4; ++nt2)
                #pragma unroll
                for (int r = 0; r < 4; ++r)
                    if (!kva[nt2]) s[m][nt2][r] = NEG;
        #pragma unroll
        for (int m = 0; m < 2; ++m) {
            #pragma unroll
            for (int r = 0; r < 4; ++r) {
                float tmx = fmaxf(fmaxf(s[m][0][r], s[m][1][r]),
                                  fmaxf(s[m][2][r], s[m][3][r]));
                tmx = fmaxf(tmx, __shfl_xor(tmx, 1));
                tmx = fmaxf(tmx, __shfl_xor(tmx, 2));
                tmx = fmaxf(tmx, __shfl_xor(tmx, 4));
                tmx = fmaxf(tmx, __shfl_xor(tmx, 8));
                const float mn = fmaxf(mst[m][r], tmx);
                const float fac = __builtin_amdgcn_exp2f(mst[m][r] - mn);
                mst[m][r] = mn; lst[m][r] *= fac;
                #pragma unroll
                for (int dt = 0; dt < 4; ++dt) acc[m][dt][r] *= fac;
                const int qr = m*16 + lg*4 + r, swz = (qr & 7) << 3;
                #pragma unroll
                for (int nt2 = 0; nt2 < 4; ++nt2)
                    Pl[wid][(qr*64 + nt2*16 + li) ^ swz] =
                        (__bf16)__builtin_amdgcn_exp2f(s[m][nt2][r] - mn);
            }
        }
        bf16x8 ap[2][2];
        #pragma unroll
        for (int m = 0; m < 2; ++m) {
            const int qr = m*16 + li, swz = (qr & 7) << 3;
            #pragma unroll
            for (int ks = 0; ks < 2; ++ks)
                ap[m][ks] = *(bf16x8*)&Pl[wid][(qr*64 + ks*32 + lg*8) ^ swz];
        }
        #pragma unroll
        for (int m = 0; m < 2; ++m) {
            f32x4 rs;
            #pragma unroll
            for (int r = 0; r < 4; ++r) rs[r] = 0.f;
            rs = MFMA16(ap[m][0], bones, rs);
            rs = MFMA16(ap[m][1], bones, rs);
            #pragma unroll
            for (int r = 0; r < 4; ++r) lst[m][r] += rs[r];
        }
        #pragma unroll
        for (int dt = 0; dt < 4; ++dt) {
            const int d = dt*16 + li, swz = (d & 7) << 3;
            #pragma unroll
            for (int ks = 0; ks < 2; ++ks) {
                bf16x8 bv = *(bf16x8*)&Vts[(d*64 + ks*32 + lg*8) ^ swz];
                #pragma unroll
                for (int m = 0; m < 2; ++m)
                    acc[m][dt] = MFMA16(ap[m][ks], bv, acc[m][dt]);
            }
        }
    }
    #pragma unroll
    for (int m = 0; m < 2; ++m) {
        #pragma unroll
        for (int r = 0; r < 4; ++r) {
            const float inv = 1.0f / lst[m][r];
            float* op = O + base + (size_t)(qrow0 + m*16 + lg*4 + r) * HD;
            #pragma unroll
            for (int dt = 0; dt < 4; ++dt) op[dt*16 + li] = acc[m][dt][r] * inv;
        }
    }
}

extern "C" void kernel_launch(void* const* d_in, const int* in_sizes, int n_in,
                              void* d_out, int out_size, void* d_ws, size_t ws_size,
                              hipStream_t stream) {
    (void)in_sizes; (void)n_in; (void)out_size;
    const float* q    = (const float*)d_in[0];
    const float* k    = (const float*)d_in[1];
    const float* v    = (const float*)d_in[2];
    const int*   vlen = (const int*)d_in[3];
    float*       out  = (float*)d_out;
    const size_t need = 2 * KV_ELEMS * sizeof(__bf16);   // 33.5 MB
    if (ws_size >= need) {
        __bf16* kfp = (__bf16*)d_ws;
        __bf16* vfp = kfp + KV_ELEMS;
        prep2<<<dim3(2048), 256, 0, stream>>>(k, v, kfp, vfp);
        fattn4<<<dim3(4096), 64, 0, stream>>>(q, kfp, vfp, vlen, out);
    } else {
        fattn_fb<<<dim3(1024), 256, 0, stream>>>(q, k, v, vlen, out);
    }
}